// Round 15
// baseline (99.802 us; speedup 1.0000x reference)
//
#include <hip/hip_runtime.h>
#include <hip/hip_bf16.h>
#include <math.h>

// Sizes fixed by the reference
#define NN 512
#define NQ 448
#define ND 64          // num_denoising
#define NC 91
#define ED 256
#define NH 8

typedef __attribute__((ext_vector_type(8))) short bf16x8;
typedef __attribute__((ext_vector_type(4))) float f32x4;

struct FreqArg { float fr[32]; };

// Device-global scratch (every cell rewritten each launch before read)
__device__ int   g_perm[NN];
__device__ float g_c0[NH];
__device__ float g_part[64 * 512];  // fold partials [(h*8+cc)*512 + d'] (d'<256: pos, >=256: rank)
__device__ float g_nr[NQ * ED];     // normal_rank = rank_emb @ pre_W^T + pre_b

__device__ inline unsigned short f2bfbits(float x) {
    __hip_bfloat16 h = __float2bfloat16(x);
    union { __hip_bfloat16 b; unsigned short u; } cv; cv.b = h; return cv.u;
}

// ---------------- K1 (290 blocks x 512): 0..223 nr tiles; 224..287 fold partials;
//                  288 scores+argsort (parallel chunked); 289 c0
__global__ __launch_bounds__(512) void k1(const float* __restrict__ logits,
                                          const float* __restrict__ attn_W,
                                          const float* __restrict__ attn_b,
                                          const float* __restrict__ post_W,
                                          const float* __restrict__ post_b,
                                          const float* __restrict__ pre_W,
                                          const float* __restrict__ pre_b,
                                          const float* __restrict__ rank_emb,
                                          float* __restrict__ out2) {
    __shared__ float smem[NQ * 33];      // 59.1 KB; nr tiles use first 48*257
    int bid = blockIdx.x, t = threadIdx.x;
    if (bid < 224) {
        // nr tile: 16 q-rows x 32 d-rows, K=256 in LDS (R10-proven)
        int q0 = (bid >> 3) * 16, d0 = (bid & 7) * 32;
        float* sP = smem;                // [32][257]
        float* sR = smem + 32 * 257;     // [16][257]
        for (int v = t; v < 32 * 256; v += 512)
            sP[(v >> 8) * 257 + (v & 255)] = pre_W[(size_t)(d0 + (v >> 8)) * ED + (v & 255)];
        for (int v = t; v < 16 * 256; v += 512)
            sR[(v >> 8) * 257 + (v & 255)] = rank_emb[(size_t)(q0 + (v >> 8)) * ED + (v & 255)];
        __syncthreads();
        int q = t >> 5, dl = t & 31;
        float acc = pre_b[d0 + dl];
#pragma unroll 8
        for (int e = 0; e < 256; ++e) acc = fmaf(sR[q * 257 + e], sP[dl * 257 + e], acc);
        g_nr[(size_t)(q0 + q) * ED + d0 + dl] = acc;
    } else if (bid < 288) {
        // fold partial (R10-proven): h = f>>3, cc = f&7, 32 c's, all 512 d' columns
        int f = bid - 224;
        int h = f >> 3, cc = f & 7;
        float* sAW = smem;
        if (t < 32) sAW[t] = attn_W[h * ED + cc * 32 + t];
        __syncthreads();
        float m = 0.f;
        const float* pw = post_W + (size_t)(cc * 32) * 512 + t;
#pragma unroll
        for (int ci = 0; ci < 32; ++ci) m = fmaf(sAW[ci], pw[(size_t)ci * 512], m);
        g_part[(size_t)f * 512 + t] = m;
    } else if (bid == 288) {
        // scores: chunked coalesced staging (stride-33 pad), per-thread row max;
        // then stable descending argsort by rank-count. sigmoid(max)==max(sigmoid).
        float* sbuf = smem;
        float mm = -INFINITY;
        for (int ck = 0; ck < 3; ++ck) {
            int cbase = ck * 32;
            __syncthreads();
            for (int idx = t; idx < NQ * 32; idx += 512) {
                int q = idx >> 5, cl = idx & 31, c = cbase + cl;
                sbuf[q * 33 + cl] = (c < NC) ? logits[(size_t)(ND + q) * NC + c] : -INFINITY;
            }
            __syncthreads();
            if (t < NQ) {
#pragma unroll 8
                for (int c = 0; c < 32; ++c) mm = fmaxf(mm, sbuf[t * 33 + c]);
            }
        }
        __syncthreads();
        if (t < NQ) sbuf[t] = mm;
        __syncthreads();
        if (t < NQ) {
            float s1 = sbuf[t];
            int r1 = 0;
            for (int jq = 0; jq < NQ; ++jq) {
                float sj = sbuf[jq];
                r1 += ((sj > s1) || (sj == s1 && jq < t)) ? 1 : 0;
            }
            g_perm[ND + r1] = ND + t;
            out2[ND + r1] = (float)(ND + t);
        }
        if (t < ND) {
            g_perm[t] = t;
            out2[t] = (float)t;
        }
    } else {
        // c0[h] = attn_b[h] + attn_W[h,:] @ post_b  (one wave per head)
        int h = t >> 6, lane = t & 63;
        float v = 0.f;
#pragma unroll
        for (int k = 0; k < 4; ++k) {
            int c = lane + 64 * k;
            v = fmaf(attn_W[h * ED + c], post_b[c], v);
        }
        for (int off = 32; off > 0; off >>= 1) v += __shfl_down(v, off, 64);
        if (lane == 0) g_c0[h] = attn_b[h] + v;
    }
}

// ---------------- K2: main. 1024 blocks x 256 thr; tile = 16 i x 16 j. Self-sufficient
// prologue: w2a reduce + WB build (from g_part), afull rows (from g_nr), perm (from g_perm).
__global__ __launch_bounds__(256) void mainv3(const float* __restrict__ boxes,
                                              const float* __restrict__ rank_emb,
                                              FreqArg fa,
                                              float* __restrict__ out) {
    __shared__ bf16x8 sWB[8][64];      // 8 KB
    __shared__ float sW[NH][260];      // w2a, padded (8.3 KB)
    __shared__ float sAf[32][9];       // afull rows: [0,16): i-rows, [16,32): j-rows
    __shared__ int   sPerm[32];
    __shared__ float sC0[NH];
    int t = threadIdx.x, bid = blockIdx.x;
    int i0 = (bid >> 5) * 16, j0 = (bid & 31) * 16;

    // w2a[h][d] = sum_cc rank-half partials
    for (int v = t; v < 2048; v += 256) {
        int h = v >> 8, d = v & 255;
        float s = 0.f;
#pragma unroll
        for (int cc = 0; cc < 8; ++cc) s += g_part[(size_t)(h * 8 + cc) * 512 + 256 + d];
        sW[h][d] = s;
    }
    // WB fragments from pos-half partials
    for (int v = t; v < 512; v += 256) {
        int s = v >> 6, lane = v & 63;
        int g = lane >> 4, hh = lane & 15;
        bf16x8 frag;
#pragma unroll
        for (int ii = 0; ii < 8; ++ii) {
            float w = 0.f;
            if (hh < NH) {
                int d = g * 64 + ((s * 4 + (ii >> 1)) << 1) + (ii & 1);
#pragma unroll
                for (int cc = 0; cc < 8; ++cc) w += g_part[(size_t)(hh * 8 + cc) * 512 + d];
            }
            frag[ii] = (short)f2bfbits(w);
        }
        sWB[s][lane] = frag;
    }
    if (t < NH) sC0[t] = g_c0[t];
    if (t >= 32 && t < 48) sPerm[t - 32] = g_perm[i0 + (t - 32)];
    else if (t >= 48 && t < 64) sPerm[t - 32] = g_perm[j0 + (t - 48)];
    __syncthreads();

    // afull rows for this tile (position-indexed; rows < ND are zero). nr includes pre_b.
    {
        int rr = t >> 3, h = t & 7;    // 32 rows x 8 heads
        int pos = (rr < 16) ? (i0 + rr) : (j0 + (rr - 16));
        float a = 0.f;
        if (pos >= ND) {
            const float* nrow = g_nr + (size_t)(pos - ND) * ED;
            for (int e = 0; e < ED; ++e) a = fmaf(nrow[e], sW[h][e], a);
        }
        sAf[rr][h] = a;
    }
    __syncthreads();

    int wv = t >> 6, lane = t & 63;
    int g = lane >> 4, r = lane & 15;
    bool jdn = (j0 < ND);
    int j = j0 + r;
    float4 b2p = ((const float4*)boxes)[j];
    float4 b2s = jdn ? b2p : ((const float4*)boxes)[sPerm[16 + r]];
    float4 cb4 = *(const float4*)(sC0 + (g & 1) * 4);
    const float eps = 1e-5f;

#pragma unroll
    for (int gi = 0; gi < 4; ++gi) {
        int iloc = wv * 4 + gi;
        int i = i0 + iloc;
        bool prm = (i >= ND) && !jdn;          // permute ONLY the [64:,64:] block
        float4 b1 = ((const float4*)boxes)[prm ? sPerm[iloc] : i];
        float4 b2 = prm ? b2s : b2p;

        float ft;
        if (g == 0)      ft = logf(fabsf(b1.x - b2.x) / (b1.z + eps) + 1.0f);
        else if (g == 1) ft = logf(fabsf(b1.y - b2.y) / (b1.w + eps) + 1.0f);
        else if (g == 2) ft = logf((b1.z + eps) / (b2.z + eps));
        else             ft = logf((b1.w + eps) / (b2.w + eps));

        f32x4 acc = {0.f, 0.f, 0.f, 0.f};
#pragma unroll
        for (int s = 0; s < 8; ++s) {
            bf16x8 bfrag;
#pragma unroll
            for (int a = 0; a < 4; ++a) {
                float rev = ft * fa.fr[s * 4 + a];
                rev -= floorf(rev);
                float sv = __builtin_amdgcn_sinf(rev);   // sin(2*pi*rev)
                float cv = __builtin_amdgcn_cosf(rev);
                bfrag[2 * a]     = (short)f2bfbits(sv);
                bfrag[2 * a + 1] = (short)f2bfbits(cv);
            }
            acc = __builtin_amdgcn_mfma_f32_16x16x32_bf16(sWB[s][lane], bfrag, acc, 0, 0, 0);
        }

        // D: row = g*4 + qq (head, valid < 8 -> g < 2), col = r (pair)
        if (g < 2) {
            const float* cbp = (const float*)&cb4;
#pragma unroll
            for (int qq = 0; qq < 4; ++qq) {
                int h = g * 4 + qq;
                float v = acc[qq] + cbp[qq] + sAf[iloc][h] + sAf[16 + r][h];
                v = v > 0.f ? v : 0.f;
                out[(size_t)h * (NN * NN) + (size_t)i * NN + j] = v;
            }
        }
    }
}

extern "C" void kernel_launch(void* const* d_in, const int* in_sizes, int n_in,
                              void* d_out, int out_size, void* d_ws, size_t ws_size,
                              hipStream_t stream) {
    const float* boxes    = (const float*)d_in[0];
    const float* logits   = (const float*)d_in[1];
    const float* rank_emb = (const float*)d_in[2];
    const float* pre_W    = (const float*)d_in[3];
    const float* pre_b    = (const float*)d_in[4];
    const float* post_W   = (const float*)d_in[5];
    const float* post_b   = (const float*)d_in[6];
    const float* attn_W   = (const float*)d_in[7];
    const float* attn_b   = (const float*)d_in[8];
    float* out = (float*)d_out;

    k1<<<290, 512, 0, stream>>>(logits, attn_W, attn_b, post_W, post_b,
                                pre_W, pre_b, rank_emb,
                                out + (size_t)NH * NN * NN);

    FreqArg fa;
    for (int k = 0; k < 32; ++k)
        fa.fr[k] = (float)(100.0 / (2.0 * M_PI) / pow(10000.0, (double)k / 32.0));

    mainv3<<<1024, 256, 0, stream>>>(boxes, rank_emb, fa, out);
}

// Round 16
// 53.638 us; speedup vs baseline: 1.8607x; 1.8607x over previous
//
#include <hip/hip_runtime.h>
#include <hip/hip_bf16.h>
#include <math.h>

// Sizes fixed by the reference
#define NN 512
#define NQ 448
#define ND 64          // num_denoising
#define NC 91
#define ED 256
#define NH 8

typedef __attribute__((ext_vector_type(8))) short bf16x8;
typedef __attribute__((ext_vector_type(4))) float f32x4;

struct FreqArg { float fr[32]; };

// Device-global scratch (every cell rewritten each launch before read)
__device__ int   g_perm[NN];
__device__ float g_c0[NH];
__device__ float g_w2a[NH * ED];    // rank-half fold (final values)
__device__ float g_nr[NQ * ED];     // normal_rank = rank_emb @ pre_W^T + pre_b
__device__ __align__(16) unsigned short g_WB[8 * 64 * 8];  // bf16 A-frags [step][lane][elem]

__device__ inline unsigned short f2bfbits(float x) {
    __hip_bfloat16 h = __float2bfloat16(x);
    union { __hip_bfloat16 b; unsigned short u; } cv; cv.b = h; return cv.u;
}

// ---------------- K1 (290 blocks x 512):
//  block 0           = scores + stable argsort (longest serial pole -> scheduled first)
//  block 1           = c0
//  blocks 2..65      = fold full-K: (h, seg) -> 64 d' columns final; seg<4 -> WB, seg>=4 -> w2a
//  blocks 66..289    = nr tiles (16 q x 32 d, K=256 in LDS)
__global__ __launch_bounds__(512) void k1(const float* __restrict__ logits,
                                          const float* __restrict__ attn_W,
                                          const float* __restrict__ attn_b,
                                          const float* __restrict__ post_W,
                                          const float* __restrict__ post_b,
                                          const float* __restrict__ pre_W,
                                          const float* __restrict__ pre_b,
                                          const float* __restrict__ rank_emb,
                                          float* __restrict__ out2) {
    __shared__ float smem[NQ * 33];      // 59.1 KB (argsort); others use a prefix
    int bid = blockIdx.x, t = threadIdx.x;
    if (bid == 0) {
        // scores: chunked coalesced staging (stride-33 pad), per-thread row max;
        // then stable descending argsort by rank-count. sigmoid(max)==max(sigmoid).
        float* sbuf = smem;
        float mm = -INFINITY;
        for (int ck = 0; ck < 3; ++ck) {
            int cbase = ck * 32;
            __syncthreads();
            for (int idx = t; idx < NQ * 32; idx += 512) {
                int q = idx >> 5, cl = idx & 31, c = cbase + cl;
                sbuf[q * 33 + cl] = (c < NC) ? logits[(size_t)(ND + q) * NC + c] : -INFINITY;
            }
            __syncthreads();
            if (t < NQ) {
#pragma unroll 8
                for (int c = 0; c < 32; ++c) mm = fmaxf(mm, sbuf[t * 33 + c]);
            }
        }
        __syncthreads();
        if (t < NQ) sbuf[t] = mm;
        __syncthreads();
        if (t < NQ) {
            float s1 = sbuf[t];
            int r1 = 0;
            for (int jq = 0; jq < NQ; ++jq) {
                float sj = sbuf[jq];
                r1 += ((sj > s1) || (sj == s1 && jq < t)) ? 1 : 0;
            }
            g_perm[ND + r1] = ND + t;
            out2[ND + r1] = (float)(ND + t);
        }
        if (t < ND) {
            g_perm[t] = t;
            out2[t] = (float)t;
        }
    } else if (bid == 1) {
        // c0[h] = attn_b[h] + attn_W[h,:] @ post_b  (one wave per head)
        int h = t >> 6, lane = t & 63;
        float v = 0.f;
#pragma unroll
        for (int k = 0; k < 4; ++k) {
            int c = lane + 64 * k;
            v = fmaf(attn_W[h * ED + c], post_b[c], v);
        }
        for (int off = 32; off > 0; off >>= 1) v += __shfl_down(v, off, 64);
        if (lane == 0) g_c0[h] = attn_b[h] + v;
    } else if (bid < 66) {
        // fold full-K: h = f>>3, seg = f&7; 64 d' columns (d' = seg*64 + dl), K=256 split
        // over 8 c-groups x 32 iters, LDS tree reduce. Writes FINAL WB / w2a values.
        int f = bid - 2;
        int h = f >> 3, seg = f & 7;
        float* sAW  = smem;          // 256
        float* sRed = smem + 256;    // [8][64]
        if (t < ED) sAW[t] = attn_W[h * ED + t];
        __syncthreads();
        int dl = t & 63, cg = t >> 6;
        float m = 0.f;
        const float* pw = post_W + (size_t)(cg * 32) * 512 + seg * 64 + dl;
#pragma unroll
        for (int ci = 0; ci < 32; ++ci) m = fmaf(sAW[cg * 32 + ci], pw[(size_t)ci * 512], m);
        sRed[cg * 64 + dl] = m;
        __syncthreads();
        if (t < 64) {
            float v = 0.f;
#pragma unroll
            for (int cg2 = 0; cg2 < 8; ++cg2) v += sRed[cg2 * 64 + t];
            if (seg < 4) {
                // d = g*64 + 2k + r, k = s*4 + (ii>>1), r = ii&1 -> WB[s][g*16+h][ii]
                int g = seg, k = t >> 1, r = t & 1;
                int s = k >> 2, ii = ((k & 3) << 1) | r;
                g_WB[s * 512 + (g * 16 + h) * 8 + ii] = f2bfbits(v);
            } else {
                g_w2a[h * ED + (seg - 4) * 64 + t] = v;
            }
        }
        // zero pad lanes (hh >= 8) of WB, one block per g (h==0, seg<4)
        if (h == 0 && seg < 4 && t < 512) {
            int s = t >> 6, hh = 8 + ((t >> 3) & 7), ii = t & 7;
            g_WB[s * 512 + (seg * 16 + hh) * 8 + ii] = 0;
        }
    } else {
        // nr tile: 16 q-rows x 32 d-rows, K=256 in LDS (R10-proven)
        int nb = bid - 66;
        int q0 = (nb >> 3) * 16, d0 = (nb & 7) * 32;
        float* sP = smem;                // [32][257]
        float* sR = smem + 32 * 257;     // [16][257]
        for (int v = t; v < 32 * 256; v += 512)
            sP[(v >> 8) * 257 + (v & 255)] = pre_W[(size_t)(d0 + (v >> 8)) * ED + (v & 255)];
        for (int v = t; v < 16 * 256; v += 512)
            sR[(v >> 8) * 257 + (v & 255)] = rank_emb[(size_t)(q0 + (v >> 8)) * ED + (v & 255)];
        __syncthreads();
        int q = t >> 5, dl = t & 31;
        float acc = pre_b[d0 + dl];
#pragma unroll 8
        for (int e = 0; e < 256; ++e) acc = fmaf(sR[q * 257 + e], sP[dl * 257 + e], acc);
        g_nr[(size_t)(q0 + q) * ED + d0 + dl] = acc;
    }
}

// ---------------- K2: main (R14-proven loop). 1024 blocks x 256; tile = 16 i x 16 j.
// Prologue: coalesced stage WB / w2a / nr rows -> LDS; afull from LDS only.
__global__ __launch_bounds__(256) void k2(const float* __restrict__ boxes,
                                          FreqArg fa,
                                          float* __restrict__ out) {
    __shared__ bf16x8 sWB[8][64];       // 8 KB
    __shared__ float sW[NH * 260];      // w2a, padded
    __shared__ float sN[32 * 260];      // nr rows of this tile, padded
    __shared__ float sAf[32][9];        // afull rows: [0,16): i-rows, [16,32): j-rows
    __shared__ int   sPerm[32];
    __shared__ float sC0[NH];
    int t = threadIdx.x, bid = blockIdx.x;
    int i0 = (bid >> 5) * 16, j0 = (bid & 31) * 16;

    ((uint4*)sWB)[t]       = ((const uint4*)g_WB)[t];
    ((uint4*)sWB)[t + 256] = ((const uint4*)g_WB)[t + 256];
    // w2a: 512 float4, coalesced
    for (int v = t; v < 512; v += 256) {
        float4 w = ((const float4*)g_w2a)[v];
        *(float4*)(sW + (v >> 6) * 260 + (v & 63) * 4) = w;
    }
    // nr rows: 32 rows x 64 float4, coalesced (rows < ND never read -> clamp)
    for (int v = t; v < 2048; v += 256) {
        int row = v >> 6, c4 = v & 63;
        int pos = (row < 16) ? (i0 + row) : (j0 + (row - 16));
        int qq = (pos >= ND) ? (pos - ND) : 0;
        float4 w = ((const float4*)(g_nr + (size_t)qq * ED))[c4];
        *(float4*)(sN + row * 260 + c4 * 4) = w;
    }
    if (t < NH) sC0[t] = g_c0[t];
    if (t >= 32 && t < 48) sPerm[t - 32] = g_perm[i0 + (t - 32)];
    else if (t >= 48 && t < 64) sPerm[t - 32] = g_perm[j0 + (t - 48)];
    __syncthreads();

    // afull rows for this tile (position-indexed; rows < ND are zero). nr includes pre_b.
    {
        int rr = t >> 3, h = t & 7;    // 32 rows x 8 heads
        int pos = (rr < 16) ? (i0 + rr) : (j0 + (rr - 16));
        float a = 0.f;
        if (pos >= ND) {
            const float* nrow = sN + rr * 260;
            const float* wrow = sW + h * 260;
#pragma unroll 8
            for (int e = 0; e < ED; ++e) a = fmaf(nrow[e], wrow[e], a);
        }
        sAf[rr][h] = a;
    }
    __syncthreads();

    int wv = t >> 6, lane = t & 63;
    int g = lane >> 4, r = lane & 15;
    bool jdn = (j0 < ND);
    int j = j0 + r;
    float4 b2p = ((const float4*)boxes)[j];
    float4 b2s = jdn ? b2p : ((const float4*)boxes)[sPerm[16 + r]];
    float4 cb4 = *(const float4*)(sC0 + (g & 1) * 4);
    const float eps = 1e-5f;

#pragma unroll
    for (int gi = 0; gi < 4; ++gi) {
        int iloc = wv * 4 + gi;
        int i = i0 + iloc;
        bool prm = (i >= ND) && !jdn;          // permute ONLY the [64:,64:] block
        float4 b1 = ((const float4*)boxes)[prm ? sPerm[iloc] : i];
        float4 b2 = prm ? b2s : b2p;

        float ft;
        if (g == 0)      ft = logf(fabsf(b1.x - b2.x) / (b1.z + eps) + 1.0f);
        else if (g == 1) ft = logf(fabsf(b1.y - b2.y) / (b1.w + eps) + 1.0f);
        else if (g == 2) ft = logf((b1.z + eps) / (b2.z + eps));
        else             ft = logf((b1.w + eps) / (b2.w + eps));

        f32x4 acc = {0.f, 0.f, 0.f, 0.f};
#pragma unroll
        for (int s = 0; s < 8; ++s) {
            bf16x8 bfrag;
#pragma unroll
            for (int a = 0; a < 4; ++a) {
                float rev = ft * fa.fr[s * 4 + a];
                rev -= floorf(rev);
                float sv = __builtin_amdgcn_sinf(rev);   // sin(2*pi*rev)
                float cv = __builtin_amdgcn_cosf(rev);
                bfrag[2 * a]     = (short)f2bfbits(sv);
                bfrag[2 * a + 1] = (short)f2bfbits(cv);
            }
            acc = __builtin_amdgcn_mfma_f32_16x16x32_bf16(sWB[s][lane], bfrag, acc, 0, 0, 0);
        }

        // D: row = g*4 + qq (head, valid < 8 -> g < 2), col = r (pair)
        if (g < 2) {
            const float* cbp = (const float*)&cb4;
#pragma unroll
            for (int qq = 0; qq < 4; ++qq) {
                int h = g * 4 + qq;
                float v = acc[qq] + cbp[qq] + sAf[iloc][h] + sAf[16 + r][h];
                v = v > 0.f ? v : 0.f;
                out[(size_t)h * (NN * NN) + (size_t)i * NN + j] = v;
            }
        }
    }
}

extern "C" void kernel_launch(void* const* d_in, const int* in_sizes, int n_in,
                              void* d_out, int out_size, void* d_ws, size_t ws_size,
                              hipStream_t stream) {
    const float* boxes    = (const float*)d_in[0];
    const float* logits   = (const float*)d_in[1];
    const float* rank_emb = (const float*)d_in[2];
    const float* pre_W    = (const float*)d_in[3];
    const float* pre_b    = (const float*)d_in[4];
    const float* post_W   = (const float*)d_in[5];
    const float* post_b   = (const float*)d_in[6];
    const float* attn_W   = (const float*)d_in[7];
    const float* attn_b   = (const float*)d_in[8];
    float* out = (float*)d_out;

    k1<<<290, 512, 0, stream>>>(logits, attn_W, attn_b, post_W, post_b,
                                pre_W, pre_b, rank_emb,
                                out + (size_t)NH * NN * NN);

    FreqArg fa;
    for (int k = 0; k < 32; ++k)
        fa.fr[k] = (float)(100.0 / (2.0 * M_PI) / pow(10000.0, (double)k / 32.0));

    k2<<<1024, 256, 0, stream>>>(boxes, fa, out);
}

// Round 17
// 46.334 us; speedup vs baseline: 2.1540x; 1.1576x over previous
//
#include <hip/hip_runtime.h>
#include <hip/hip_bf16.h>
#include <math.h>

// Sizes fixed by the reference
#define NN 512
#define NQ 448
#define ND 64          // num_denoising
#define NC 91
#define ED 256
#define NH 8

typedef __attribute__((ext_vector_type(8))) short bf16x8;
typedef __attribute__((ext_vector_type(4))) float f32x4;

struct FreqArg { float fr[32]; };

// Device-global scratch (every cell rewritten each launch before read)
__device__ int   g_perm[NN];
__device__ float g_c0[NH];
__device__ float g_w2a[NH * ED];    // rank-half fold (final values)
__device__ float g_nr[NQ * ED];     // normal_rank = rank_emb @ pre_W^T + pre_b
__device__ float g_afull[NN * NH];
__device__ __align__(16) unsigned short g_WB[8 * 64 * 8];  // bf16 A-frags [step][lane][elem]

__device__ inline unsigned short f2bfbits(float x) {
    __hip_bfloat16 h = __float2bfloat16(x);
    union { __hip_bfloat16 b; unsigned short u; } cv; cv.b = h; return cv.u;
}

// ---------------- K1 (290 blocks x 512)  [R16-proven]:
//  block 0 = scores + stable argsort; block 1 = c0;
//  blocks 2..65 = fold full-K -> final WB / w2a; blocks 66..289 = nr tiles
__global__ __launch_bounds__(512) void k1(const float* __restrict__ logits,
                                          const float* __restrict__ attn_W,
                                          const float* __restrict__ attn_b,
                                          const float* __restrict__ post_W,
                                          const float* __restrict__ post_b,
                                          const float* __restrict__ pre_W,
                                          const float* __restrict__ pre_b,
                                          const float* __restrict__ rank_emb,
                                          float* __restrict__ out2) {
    __shared__ float smem[NQ * 33];      // 59.1 KB (argsort); others use a prefix
    int bid = blockIdx.x, t = threadIdx.x;
    if (bid == 0) {
        float* sbuf = smem;
        float mm = -INFINITY;
        for (int ck = 0; ck < 3; ++ck) {
            int cbase = ck * 32;
            __syncthreads();
            for (int idx = t; idx < NQ * 32; idx += 512) {
                int q = idx >> 5, cl = idx & 31, c = cbase + cl;
                sbuf[q * 33 + cl] = (c < NC) ? logits[(size_t)(ND + q) * NC + c] : -INFINITY;
            }
            __syncthreads();
            if (t < NQ) {
#pragma unroll 8
                for (int c = 0; c < 32; ++c) mm = fmaxf(mm, sbuf[t * 33 + c]);
            }
        }
        __syncthreads();
        if (t < NQ) sbuf[t] = mm;
        __syncthreads();
        if (t < NQ) {
            float s1 = sbuf[t];
            int r1 = 0;
            for (int jq = 0; jq < NQ; ++jq) {
                float sj = sbuf[jq];
                r1 += ((sj > s1) || (sj == s1 && jq < t)) ? 1 : 0;
            }
            g_perm[ND + r1] = ND + t;
            out2[ND + r1] = (float)(ND + t);
        }
        if (t < ND) {
            g_perm[t] = t;
            out2[t] = (float)t;
        }
    } else if (bid == 1) {
        int h = t >> 6, lane = t & 63;
        float v = 0.f;
#pragma unroll
        for (int k = 0; k < 4; ++k) {
            int c = lane + 64 * k;
            v = fmaf(attn_W[h * ED + c], post_b[c], v);
        }
        for (int off = 32; off > 0; off >>= 1) v += __shfl_down(v, off, 64);
        if (lane == 0) g_c0[h] = attn_b[h] + v;
    } else if (bid < 66) {
        int f = bid - 2;
        int h = f >> 3, seg = f & 7;
        float* sAW  = smem;
        float* sRed = smem + 256;
        if (t < ED) sAW[t] = attn_W[h * ED + t];
        __syncthreads();
        int dl = t & 63, cg = t >> 6;
        float m = 0.f;
        const float* pw = post_W + (size_t)(cg * 32) * 512 + seg * 64 + dl;
#pragma unroll
        for (int ci = 0; ci < 32; ++ci) m = fmaf(sAW[cg * 32 + ci], pw[(size_t)ci * 512], m);
        sRed[cg * 64 + dl] = m;
        __syncthreads();
        if (t < 64) {
            float v = 0.f;
#pragma unroll
            for (int cg2 = 0; cg2 < 8; ++cg2) v += sRed[cg2 * 64 + t];
            if (seg < 4) {
                int g = seg, k = t >> 1, r = t & 1;
                int s = k >> 2, ii = ((k & 3) << 1) | r;
                g_WB[s * 512 + (g * 16 + h) * 8 + ii] = f2bfbits(v);
            } else {
                g_w2a[h * ED + (seg - 4) * 64 + t] = v;
            }
        }
        if (h == 0 && seg < 4 && t < 512) {
            int s = t >> 6, hh = 8 + ((t >> 3) & 7), ii = t & 7;
            g_WB[s * 512 + (seg * 16 + hh) * 8 + ii] = 0;
        }
    } else {
        int nb = bid - 66;
        int q0 = (nb >> 3) * 16, d0 = (nb & 7) * 32;
        float* sP = smem;                // [32][257]
        float* sR = smem + 32 * 257;     // [16][257]
        for (int v = t; v < 32 * 256; v += 512)
            sP[(v >> 8) * 257 + (v & 255)] = pre_W[(size_t)(d0 + (v >> 8)) * ED + (v & 255)];
        for (int v = t; v < 16 * 256; v += 512)
            sR[(v >> 8) * 257 + (v & 255)] = rank_emb[(size_t)(q0 + (v >> 8)) * ED + (v & 255)];
        __syncthreads();
        int q = t >> 5, dl = t & 31;
        float acc = pre_b[d0 + dl];
#pragma unroll 8
        for (int e = 0; e < 256; ++e) acc = fmaf(sR[q * 257 + e], sP[dl * 257 + e], acc);
        g_nr[(size_t)(q0 + q) * ED + d0 + dl] = acc;
    }
}

// ---------------- K2 (57 blocks x 256): afull once. Block = 8 q-rows; float4 LDS reads,
// 4 threads per output, shfl-reduce. Block 56 zeros denoising rows.
#define SRD 264   // float stride per row: multiple of 4 (16B-aligned float4 rows)
__global__ __launch_bounds__(256) void k2afull() {
    __shared__ float sW[NH * SRD];
    __shared__ float sN[8 * SRD];
    int bid = blockIdx.x, t = threadIdx.x;
    if (bid < 56) {
        int q0 = bid * 8;
        for (int v = t; v < 512; v += 256) {           // w2a: 512 float4, coalesced
            float4 w = ((const float4*)g_w2a)[v];
            *(float4*)(sW + (v >> 6) * SRD + (v & 63) * 4) = w;
        }
        for (int v = t; v < 512; v += 256) {           // nr rows q0..q0+7
            int row = v >> 6, c4 = v & 63;
            float4 w = ((const float4*)(g_nr + (size_t)(q0 + row) * ED))[c4];
            *(float4*)(sN + row * SRD + c4 * 4) = w;
        }
        __syncthreads();
        int o = t >> 2, sub = t & 3;                   // 64 outputs (8q x 8h), 4 threads each
        int q = o >> 3, h = o & 7;
        const float* nrow = sN + q * SRD;
        const float* wrow = sW + h * SRD;
        float a = 0.f;
#pragma unroll
        for (int k4 = 0; k4 < 16; ++k4) {
            int e4 = sub + 4 * k4;
            float4 x = *(const float4*)(nrow + e4 * 4);
            float4 y = *(const float4*)(wrow + e4 * 4);
            a = fmaf(x.x, y.x, a); a = fmaf(x.y, y.y, a);
            a = fmaf(x.z, y.z, a); a = fmaf(x.w, y.w, a);
        }
        a += __shfl_xor(a, 1, 64);
        a += __shfl_xor(a, 2, 64);
        if (sub == 0) g_afull[(size_t)(ND + q0 + q) * NH + h] = a;
    } else {
        for (int v = t; v < ND * NH; v += 256) g_afull[v] = 0.f;
    }
}

// ---------------- K3: MFMA main (R10-proven, 4096 blocks x 256). Wave = 16 pairs;
// A = weights (rows = heads), B = in-register sine features; 8 x K=32 steps.
__global__ __launch_bounds__(256) void relation_main(const float* __restrict__ boxes,
                                                     FreqArg fa,
                                                     float* __restrict__ out) {
    __shared__ bf16x8 sWB[8][64];
    int t = threadIdx.x;
    ((uint4*)sWB)[t]       = ((const uint4*)g_WB)[t];
    ((uint4*)sWB)[t + 256] = ((const uint4*)g_WB)[t + 256];
    __syncthreads();

    int wave = t >> 6, lane = t & 63;
    int g = lane >> 4, r = lane & 15;
    int i = blockIdx.x >> 3;
    int j = ((blockIdx.x & 7) << 6) + (wave << 4) + r;

    int pi = i, pj = j;
    if (i >= ND && j >= ND) { pi = g_perm[i]; pj = g_perm[j]; }   // permute ONLY [64:,64:]
    float4 b1 = ((const float4*)boxes)[pi];
    float4 b2 = ((const float4*)boxes)[pj];
    const float eps = 1e-5f;
    float ft;
    if (g == 0)      ft = logf(fabsf(b1.x - b2.x) / (b1.z + eps) + 1.0f);
    else if (g == 1) ft = logf(fabsf(b1.y - b2.y) / (b1.w + eps) + 1.0f);
    else if (g == 2) ft = logf((b1.z + eps) / (b2.z + eps));
    else             ft = logf((b1.w + eps) / (b2.w + eps));

    f32x4 acc = {0.f, 0.f, 0.f, 0.f};
#pragma unroll
    for (int s = 0; s < 8; ++s) {
        bf16x8 bfrag;
#pragma unroll
        for (int a = 0; a < 4; ++a) {
            float rev = ft * fa.fr[s * 4 + a];
            rev -= floorf(rev);
            float sv = __builtin_amdgcn_sinf(rev);   // sin(2*pi*rev)
            float cv = __builtin_amdgcn_cosf(rev);
            bfrag[2 * a]     = (short)f2bfbits(sv);
            bfrag[2 * a + 1] = (short)f2bfbits(cv);
        }
        acc = __builtin_amdgcn_mfma_f32_16x16x32_bf16(sWB[s][lane], bfrag, acc, 0, 0, 0);
    }

    // D: row = g*4 + q (head, valid < 8 -> g < 2), col = r (pair)
    if (g < 2) {
        float4 cb = *(const float4*)(g_c0 + g * 4);
        float4 ai = *(const float4*)(g_afull + i * NH + g * 4);
        float4 aj = *(const float4*)(g_afull + j * NH + g * 4);
        const float* cbp = (const float*)&cb;
        const float* aip = (const float*)&ai;
        const float* ajp = (const float*)&aj;
#pragma unroll
        for (int q = 0; q < 4; ++q) {
            int h = g * 4 + q;
            float v = acc[q] + cbp[q] + aip[q] + ajp[q];
            v = v > 0.f ? v : 0.f;
            out[(size_t)h * (NN * NN) + i * NN + j] = v;
        }
    }
}

extern "C" void kernel_launch(void* const* d_in, const int* in_sizes, int n_in,
                              void* d_out, int out_size, void* d_ws, size_t ws_size,
                              hipStream_t stream) {
    const float* boxes    = (const float*)d_in[0];
    const float* logits   = (const float*)d_in[1];
    const float* rank_emb = (const float*)d_in[2];
    const float* pre_W    = (const float*)d_in[3];
    const float* pre_b    = (const float*)d_in[4];
    const float* post_W   = (const float*)d_in[5];
    const float* post_b   = (const float*)d_in[6];
    const float* attn_W   = (const float*)d_in[7];
    const float* attn_b   = (const float*)d_in[8];
    float* out = (float*)d_out;

    k1<<<290, 512, 0, stream>>>(logits, attn_W, attn_b, post_W, post_b,
                                pre_W, pre_b, rank_emb,
                                out + (size_t)NH * NN * NN);
    k2afull<<<57, 256, 0, stream>>>();

    FreqArg fa;
    for (int k = 0; k < 32; ++k)
        fa.fr[k] = (float)(100.0 / (2.0 * M_PI) / pow(10000.0, (double)k / 32.0));

    relation_main<<<4096, 256, 0, stream>>>(boxes, fa, out);
}

// Round 18
// 46.005 us; speedup vs baseline: 2.1694x; 1.0071x over previous
//
#include <hip/hip_runtime.h>
#include <hip/hip_bf16.h>
#include <math.h>

// Sizes fixed by the reference
#define NN 512
#define NQ 448
#define ND 64          // num_denoising
#define NC 91
#define ED 256
#define NH 8

typedef __attribute__((ext_vector_type(8))) short bf16x8;
typedef __attribute__((ext_vector_type(4))) float f32x4;

struct FreqArg { float fr[32]; };

// Device-global scratch
__device__ int   g_perm[NN];
__device__ float g_c0[NH];
__device__ float g_afull[NN * NH];
__device__ float g_part[64 * 512];  // fold partials: [(h*8+cc)*512 + d']  (d'<256: pos, >=256: rank)
__device__ float g_scores[NQ];      // raw max-logit (sigmoid monotone -> same order)
__device__ float g_nr[NQ * ED];     // normal_rank = rank_emb @ pre_W^T + pre_b
__device__ __align__(16) unsigned short g_WB[8 * 64 * 8];  // bf16 A-frags [step][lane][elem]

__device__ inline unsigned short f2bfbits(float x) {
    __hip_bfloat16 h = __float2bfloat16(x);
    union { __hip_bfloat16 b; unsigned short u; } cv; cv.b = h; return cv.u;
}

// ---------------- K1: 0..223 nr tiles; 224..287 fold partials; 288..295 scores; 296 c0
__global__ __launch_bounds__(512) void precomp1(const float* __restrict__ logits,
                                                const float* __restrict__ attn_W,
                                                const float* __restrict__ attn_b,
                                                const float* __restrict__ post_W,
                                                const float* __restrict__ post_b,
                                                const float* __restrict__ pre_W,
                                                const float* __restrict__ pre_b,
                                                const float* __restrict__ rank_emb) {
    __shared__ float smem[48 * 257];     // nr: sP[32][257] + sR[16][257]; fold: first 32 floats
    int bid = blockIdx.x;
    int t = threadIdx.x;
    if (bid < 224) {
        // nr tile: 16 q-rows x 32 d-rows, K=256 in LDS
        int q0 = (bid >> 3) * 16, d0 = (bid & 7) * 32;
        float* sP = smem;                    // [32][257] pre_W rows
        float* sR = smem + 32 * 257;         // [16][257] rank_emb rows
        for (int v = t; v < 32 * 256; v += 512)
            sP[(v >> 8) * 257 + (v & 255)] = pre_W[(size_t)(d0 + (v >> 8)) * ED + (v & 255)];
        for (int v = t; v < 16 * 256; v += 512)
            sR[(v >> 8) * 257 + (v & 255)] = rank_emb[(size_t)(q0 + (v >> 8)) * ED + (v & 255)];
        __syncthreads();
        int q = t >> 5, dl = t & 31;
        float acc = pre_b[d0 + dl];
#pragma unroll 8
        for (int e = 0; e < 256; ++e) acc = fmaf(sR[q * 257 + e], sP[dl * 257 + e], acc);
        g_nr[(size_t)(q0 + q) * ED + d0 + dl] = acc;
    } else if (bid < 288) {
        int f = bid - 224;
        int h = f >> 3, cc = f & 7;
        float* sAW = smem;
        if (t < 32) sAW[t] = attn_W[h * ED + cc * 32 + t];
        __syncthreads();
        float m = 0.f;
        const float* pw = post_W + (size_t)(cc * 32) * 512 + t;
#pragma unroll
        for (int ci = 0; ci < 32; ++ci) m = fmaf(sAW[ci], pw[(size_t)ci * 512], m);
        g_part[(size_t)f * 512 + t] = m;
    } else if (bid < 296) {
        int W = (bid - 288) * 8 + (t >> 6);   // wave id 0..63
        int lane = t & 63;
        for (int qi = 0; qi < 7; ++qi) {
            int q = W * 7 + qi;              // 0..447
            const float* row = logits + (size_t)(ND + q) * NC;
            float m = (lane < NC) ? row[lane] : -INFINITY;
            int c2 = lane + 64;
            if (c2 < NC) m = fmaxf(m, row[c2]);
            for (int off = 32; off > 0; off >>= 1) m = fmaxf(m, __shfl_down(m, off, 64));
            if (lane == 0) g_scores[q] = m;  // sigmoid(max)==max(sigmoid): rank raw logits
        }
    } else {
        int h = t >> 6, lane = t & 63;
        float v = 0.f;
#pragma unroll
        for (int k = 0; k < 4; ++k) {
            int c = lane + 64 * k;
            v = fmaf(attn_W[h * ED + c], post_b[c], v);
        }
        for (int off = 32; off > 0; off >>= 1) v += __shfl_down(v, off, 64);
        if (lane == 0) g_c0[h] = attn_b[h] + v;
    }
}

// ---------------- K2: 0..55 afull tiles (8 q each); 56..57 WB pack; 58 argsort
__global__ __launch_bounds__(256) void precomp2(float* __restrict__ out2) {
    int bid = blockIdx.x;
    int t = threadIdx.x;
    if (bid < 56) {
        __shared__ float sW[NH * 260];   // w2a[h][d] (redundant per-block reduce)
        __shared__ float sN[NH * 260];   // nr rows of this q-tile
        int q0 = bid * 8;
        for (int v = t; v < 2048; v += 256) {
            int h = v >> 8, d = v & 255;
            float s = 0.f;
#pragma unroll
            for (int cc = 0; cc < 8; ++cc) s += g_part[(size_t)(h * 8 + cc) * 512 + 256 + d];
            sW[h * 260 + d] = s;
        }
        for (int v = t; v < 2048; v += 256)
            sN[(v >> 8) * 260 + (v & 255)] = g_nr[(size_t)(q0 + (v >> 8)) * ED + (v & 255)];
        __syncthreads();
        // 64 outputs (8q x 8h), 4 threads each over interleaved e = sub + 4*e2
        int o = t >> 2, sub = t & 3;
        int q = o >> 3, h = o & 7;
        float a = 0.f;
#pragma unroll 8
        for (int e2 = 0; e2 < 64; ++e2) {
            int e = sub + 4 * e2;
            a = fmaf(sN[q * 260 + e], sW[h * 260 + e], a);
        }
        a += __shfl_xor(a, 1, 64);
        a += __shfl_xor(a, 2, 64);
        if (sub == 0) g_afull[(size_t)(ND + q0 + q) * NH + h] = a;
    } else if (bid < 58) {
        // WB pack straight from fold partials
        for (int vv = t; vv < 2048; vv += 256) {
            int v = (bid - 56) * 2048 + vv;
            int s = v >> 9;
            int lane = (v >> 3) & 63;
            int ii = v & 7;
            int g = lane >> 4, hh = lane & 15;
            int k = s * 4 + (ii >> 1), r = ii & 1;
            int d = g * 64 + 2 * k + r;
            float w = 0.f;
            if (hh < NH) {
#pragma unroll
                for (int cc = 0; cc < 8; ++cc) w += g_part[(size_t)(hh * 8 + cc) * 512 + d];
            }
            g_WB[v] = f2bfbits(w);
        }
    } else {
        // stable descending argsort by rank-count from g_scores
        __shared__ float sc[NQ];
        for (int v = t; v < NQ; v += 256) sc[v] = g_scores[v];
        __syncthreads();
        int q1 = t, q2 = t + 256;
        float s1 = sc[q1];
        float s2 = (q2 < NQ) ? sc[q2] : 0.f;
        int r1 = 0, r2 = 0;
        for (int j = 0; j < NQ; ++j) {
            float sj = sc[j];
            r1 += ((sj > s1) || (sj == s1 && j < q1)) ? 1 : 0;
            r2 += ((sj > s2) || (sj == s2 && j < q2)) ? 1 : 0;
        }
        g_perm[ND + r1] = ND + q1;
        out2[ND + r1] = (float)(ND + q1);
        if (q2 < NQ) {
            g_perm[ND + r2] = ND + q2;
            out2[ND + r2] = (float)(ND + q2);
        }
        if (t < ND) {
            g_perm[t] = t;
            out2[t] = (float)t;
            for (int h = 0; h < NH; ++h) g_afull[t * NH + h] = 0.f;
        }
    }
}

// ---------------- K3: MFMA main kernel. Wave = 16 pairs; A = weights (rows = heads),
//                     B = in-register sine features (cols = pairs); 8 x K=32 steps.
__global__ __launch_bounds__(256) void relation_main(const float* __restrict__ boxes,
                                                     FreqArg fa,
                                                     float* __restrict__ out) {
    __shared__ bf16x8 sWB[8][64];
    int t = threadIdx.x;
    ((uint4*)sWB)[t]       = ((const uint4*)g_WB)[t];
    ((uint4*)sWB)[t + 256] = ((const uint4*)g_WB)[t + 256];
    __syncthreads();

    int wave = t >> 6, lane = t & 63;
    int g = lane >> 4, r = lane & 15;
    int i = blockIdx.x >> 3;
    int j = ((blockIdx.x & 7) << 6) + (wave << 4) + r;

    int pi = i, pj = j;
    if (i >= ND && j >= ND) { pi = g_perm[i]; pj = g_perm[j]; }   // permute ONLY the [64:,64:] block
    float4 b1 = ((const float4*)boxes)[pi];
    float4 b2 = ((const float4*)boxes)[pj];
    const float eps = 1e-5f;
    float ft;
    if (g == 0)      ft = logf(fabsf(b1.x - b2.x) / (b1.z + eps) + 1.0f);
    else if (g == 1) ft = logf(fabsf(b1.y - b2.y) / (b1.w + eps) + 1.0f);
    else if (g == 2) ft = logf((b1.z + eps) / (b2.z + eps));
    else             ft = logf((b1.w + eps) / (b2.w + eps));

    f32x4 acc = {0.f, 0.f, 0.f, 0.f};
#pragma unroll
    for (int s = 0; s < 8; ++s) {
        bf16x8 bfrag;
#pragma unroll
        for (int a = 0; a < 4; ++a) {
            float rev = ft * fa.fr[s * 4 + a];
            rev -= floorf(rev);
            float sv = __builtin_amdgcn_sinf(rev);   // sin(2*pi*rev)
            float cv = __builtin_amdgcn_cosf(rev);
            bfrag[2 * a]     = (short)f2bfbits(sv);
            bfrag[2 * a + 1] = (short)f2bfbits(cv);
        }
        acc = __builtin_amdgcn_mfma_f32_16x16x32_bf16(sWB[s][lane], bfrag, acc, 0, 0, 0);
    }

    // D: row = g*4 + q (head, valid < 8 -> g < 2), col = r (pair)
    if (g < 2) {
        float4 cb = *(const float4*)(g_c0 + g * 4);
        float4 ai = *(const float4*)(g_afull + i * NH + g * 4);
        float4 aj = *(const float4*)(g_afull + j * NH + g * 4);
        const float* cbp = (const float*)&cb;
        const float* aip = (const float*)&ai;
        const float* ajp = (const float*)&aj;
#pragma unroll
        for (int q = 0; q < 4; ++q) {
            int h = g * 4 + q;
            float v = acc[q] + cbp[q] + aip[q] + ajp[q];
            v = v > 0.f ? v : 0.f;
            out[(size_t)h * (NN * NN) + i * NN + j] = v;
        }
    }
}

extern "C" void kernel_launch(void* const* d_in, const int* in_sizes, int n_in,
                              void* d_out, int out_size, void* d_ws, size_t ws_size,
                              hipStream_t stream) {
    const float* boxes    = (const float*)d_in[0];
    const float* logits   = (const float*)d_in[1];
    const float* rank_emb = (const float*)d_in[2];
    const float* pre_W    = (const float*)d_in[3];
    const float* pre_b    = (const float*)d_in[4];
    const float* post_W   = (const float*)d_in[5];
    const float* post_b   = (const float*)d_in[6];
    const float* attn_W   = (const float*)d_in[7];
    const float* attn_b   = (const float*)d_in[8];
    float* out = (float*)d_out;

    precomp1<<<297, 512, 0, stream>>>(logits, attn_W, attn_b, post_W, post_b,
                                      pre_W, pre_b, rank_emb);
    precomp2<<<59, 256, 0, stream>>>(out + (size_t)NH * NN * NN);

    FreqArg fa;
    for (int k = 0; k < 32; ++k)
        fa.fr[k] = (float)(100.0 / (2.0 * M_PI) / pow(10000.0, (double)k / 32.0));

    relation_main<<<4096, 256, 0, stream>>>(boxes, fa, out);
}